// Round 7
// baseline (223.923 us; speedup 1.0000x reference)
//
#include <hip/hip_runtime.h>
#include <cmath>

#define HH 512
#define WW 512
#define TW 32
#define TH 32          /* output rows per chunk */
#define NCHUNK 4       /* chunks per block: stripe = 128 rows */
#define STRIPE (TH * NCHUNK)
#define INH 42         /* TH + 10 halo rows */
#define HPS 36         /* hp row stride in dwords (mult of 4) */
#define C1F 0.0001f
#define C2F 0.0009f

struct GaussW { float w[11]; };

__global__ __launch_bounds__(256) void ssim_tile_kernel(
    const float* __restrict__ pred, const float* __restrict__ targ,
    float* __restrict__ partial, GaussW gw)
{
    // 4 fields: mu1-h, mu2-h, (p^2+t^2)-h, (p*t)-h   -> 24.2 KB
    __shared__ __align__(16) float hp[4][INH][HPS];
    __shared__ float wred[4];

    const int tid = threadIdx.x;
    const int bx = blockIdx.x, by = blockIdx.y, bz = blockIdx.z;
    const int gx0 = bx * TW;
    const size_t plane = (size_t)bz * (size_t)(HH * WW);

    const bool xinterior = (bx > 0) && (bx < (WW / TW) - 1);

    float local = 0.f;

    for (int ci = 0; ci < NCHUNK; ci++) {
        const int gy0 = by * STRIPE + ci * TH - 5;

        // ---- Phase B: horizontal Gaussian directly from global memory ----
        // 336 tasks: 42 rows x 8 col-groups, each computes 4 output cols.
        if (xinterior) {
            for (int i = tid; i < INH * 8; i += 256) {
                int r = i >> 3;
                int c0 = (i & 7) << 2;
                int gr = gy0 + r;
                // p[m]/t[m] hold input col c0-6+m, m=0..15 (need m=1..14)
                float p[16], t[16];
                if ((unsigned)gr < (unsigned)HH) {
                    const float* prow = pred + plane + (size_t)gr * WW + (gx0 + c0 - 6);
                    const float* trow = targ + plane + (size_t)gr * WW + (gx0 + c0 - 6);
                    *(float2*)&p[0]  = *(const float2*)(prow);
                    *(float4*)&p[2]  = *(const float4*)(prow + 2);
                    *(float4*)&p[6]  = *(const float4*)(prow + 6);
                    *(float4*)&p[10] = *(const float4*)(prow + 10);
                    *(float2*)&p[14] = *(const float2*)(prow + 14);
                    *(float2*)&t[0]  = *(const float2*)(trow);
                    *(float4*)&t[2]  = *(const float4*)(trow + 2);
                    *(float4*)&t[6]  = *(const float4*)(trow + 6);
                    *(float4*)&t[10] = *(const float4*)(trow + 10);
                    *(float2*)&t[14] = *(const float2*)(trow + 14);
                } else {
                    #pragma unroll
                    for (int m = 0; m < 16; m++) { p[m] = 0.f; t[m] = 0.f; }
                }

                float sq[14], pt[14];
                #pragma unroll
                for (int m = 0; m < 14; m++) {
                    float pv = p[m + 1], tv = t[m + 1];
                    sq[m] = pv * pv + tv * tv;
                    pt[m] = pv * tv;
                }

                float s1[4] = {0,0,0,0}, s2[4] = {0,0,0,0};
                float s3[4] = {0,0,0,0}, s4[4] = {0,0,0,0};
                #pragma unroll
                for (int k = 0; k < 11; k++) {
                    float wk = gw.w[k];
                    #pragma unroll
                    for (int o = 0; o < 4; o++) {
                        s1[o] += wk * p[o + k + 1];
                        s2[o] += wk * t[o + k + 1];
                        s3[o] += wk * sq[o + k];
                        s4[o] += wk * pt[o + k];
                    }
                }
                *(float4*)&hp[0][r][c0] = make_float4(s1[0], s1[1], s1[2], s1[3]);
                *(float4*)&hp[1][r][c0] = make_float4(s2[0], s2[1], s2[2], s2[3]);
                *(float4*)&hp[2][r][c0] = make_float4(s3[0], s3[1], s3[2], s3[3]);
                *(float4*)&hp[3][r][c0] = make_float4(s4[0], s4[1], s4[2], s4[3]);
            }
        } else {
            for (int i = tid; i < INH * 8; i += 256) {
                int r = i >> 3;
                int c0 = (i & 7) << 2;
                int gr = gy0 + r;
                float p[14], t[14];
                if ((unsigned)gr < (unsigned)HH) {
                    const size_t rb = plane + (size_t)gr * WW;
                    int cbase = gx0 + c0 - 5;
                    #pragma unroll
                    for (int m = 0; m < 14; m++) {
                        int gc = cbase + m;
                        int cc = min(max(gc, 0), WW - 1);
                        bool in = (unsigned)gc < (unsigned)WW;
                        float pv = pred[rb + cc];
                        float tv = targ[rb + cc];
                        p[m] = in ? pv : 0.f;
                        t[m] = in ? tv : 0.f;
                    }
                } else {
                    #pragma unroll
                    for (int m = 0; m < 14; m++) { p[m] = 0.f; t[m] = 0.f; }
                }

                float s1[4] = {0,0,0,0}, s2[4] = {0,0,0,0};
                float s3[4] = {0,0,0,0}, s4[4] = {0,0,0,0};
                #pragma unroll
                for (int k = 0; k < 11; k++) {
                    float wk = gw.w[k];
                    #pragma unroll
                    for (int o = 0; o < 4; o++) {
                        float pv = p[o + k], tv = t[o + k];
                        float wp = wk * pv, wt = wk * tv;
                        s1[o] += wp;
                        s2[o] += wt;
                        s3[o] += wp * pv + wt * tv;
                        s4[o] += wp * tv;
                    }
                }
                *(float4*)&hp[0][r][c0] = make_float4(s1[0], s1[1], s1[2], s1[3]);
                *(float4*)&hp[1][r][c0] = make_float4(s2[0], s2[1], s2[2], s2[3]);
                *(float4*)&hp[2][r][c0] = make_float4(s3[0], s3[1], s3[2], s3[3]);
                *(float4*)&hp[3][r][c0] = make_float4(s4[0], s4[1], s4[2], s4[3]);
            }
        }
        __syncthreads();

        // ---- Phase C: vertical Gaussian, 4 rows x 1 col per lane + SSIM ----
        {
            int c  = tid & 31;          // 0..31
            int r0 = (tid >> 5) << 2;   // 0..28

            float acc[4][4];
            #pragma unroll
            for (int f = 0; f < 4; f++)
                #pragma unroll
                for (int rr = 0; rr < 4; rr++)
                    acc[f][rr] = 0.f;

            #pragma unroll
            for (int jj = 0; jj < 14; jj++) {
                float v[4];
                #pragma unroll
                for (int f = 0; f < 4; f++)
                    v[f] = hp[f][r0 + jj][c];
                #pragma unroll
                for (int rr = 0; rr < 4; rr++) {
                    int k = jj - rr;
                    if (k >= 0 && k < 11) {
                        float wk = gw.w[k];
                        #pragma unroll
                        for (int f = 0; f < 4; f++)
                            acc[f][rr] += wk * v[f];
                    }
                }
            }

            #pragma unroll
            for (int rr = 0; rr < 4; rr++) {
                float m1 = acc[0][rr], m2 = acc[1][rr];
                float e3 = acc[2][rr], e12 = acc[3][rr];
                float m1s = m1 * m1, m2s = m2 * m2, m12 = m1 * m2;
                float num = (2.f * m12 + C1F) * (2.f * (e12 - m12) + C2F);
                float den = (m1s + m2s + C1F) * (e3 - m1s - m2s + C2F);
                local += num * __builtin_amdgcn_rcpf(den);
            }
        }
        __syncthreads();   // hp reused next chunk
    }

    // ---- block reduction ----
    #pragma unroll
    for (int off = 32; off > 0; off >>= 1)
        local += __shfl_down(local, off, 64);
    int lane = tid & 63, wid = tid >> 6;
    if (lane == 0) wred[wid] = local;
    __syncthreads();
    if (tid == 0) {
        int bid = (bz * gridDim.y + by) * gridDim.x + bx;
        partial[bid] = wred[0] + wred[1] + wred[2] + wred[3];
    }
}

__global__ __launch_bounds__(1024) void ssim_finalize_kernel(
    const float* __restrict__ partial, int n, float inv_count,
    float* __restrict__ out)
{
    __shared__ float sm[16];
    float s = 0.f;
    for (int i = threadIdx.x; i < n; i += 1024)
        s += partial[i];
    #pragma unroll
    for (int off = 32; off > 0; off >>= 1)
        s += __shfl_down(s, off, 64);
    int lane = threadIdx.x & 63, wid = threadIdx.x >> 6;
    if (lane == 0) sm[wid] = s;
    __syncthreads();
    if (threadIdx.x == 0) {
        float tot = 0.f;
        #pragma unroll
        for (int k = 0; k < 16; k++) tot += sm[k];
        out[0] = 1.0f - tot * inv_count;
    }
}

extern "C" void kernel_launch(void* const* d_in, const int* in_sizes, int n_in,
                              void* d_out, int out_size, void* d_ws, size_t ws_size,
                              hipStream_t stream)
{
    const float* pred = (const float*)d_in[0];
    const float* targ = (const float*)d_in[1];
    float* out = (float*)d_out;
    float* partial = (float*)d_ws;

    const int total = in_sizes[0];                 // 16*3*512*512 = 12582912
    const int nplanes = total / (HH * WW);         // 48

    GaussW gw;
    double g[11], s = 0.0;
    for (int i = 0; i < 11; i++) {
        double d = (double)(i - 5);
        g[i] = exp(-d * d / 4.5);
        s += g[i];
    }
    for (int i = 0; i < 11; i++) gw.w[i] = (float)(g[i] / s);

    dim3 grid(WW / TW, HH / STRIPE, nplanes);      // 16 x 4 x 48 = 3072 blocks
    ssim_tile_kernel<<<grid, 256, 0, stream>>>(pred, targ, partial, gw);

    const int nblocks = (WW / TW) * (HH / STRIPE) * nplanes;
    const float inv_count = 1.0f / (float)total;
    ssim_finalize_kernel<<<1, 1024, 0, stream>>>(partial, nblocks, inv_count, out);
}

// Round 8
// 203.451 us; speedup vs baseline: 1.1006x; 1.1006x over previous
//
#include <hip/hip_runtime.h>
#include <cmath>

#define HH 512
#define WW 512
#define TW 32
#define TH 32
#define INH 42          /* TH + 10 halo rows */
#define HPC 35          /* hp col stride (in 4-dword field groups) */
#define C1F 0.0001f
#define C2F 0.0009f

struct GaussW { float w[11]; };

// hp layout: hp4[r][c][f], addr dwords = (r*HPC + c)*4 + f
// One float4 per (row, col) holds all 4 fields: (m1h, m2h, sqh, pth).

__device__ __forceinline__ void hconv4(
    const float p[16], const float t[16], float4 out[4], const GaussW& gw)
{
    // inputs p[m],t[m] = col c0-6+m ; valid window m=1..14
    float sq[14], pt[14];
    #pragma unroll
    for (int m = 0; m < 14; m++) {
        float pv = p[m + 1], tv = t[m + 1];
        sq[m] = pv * pv + tv * tv;
        pt[m] = pv * tv;
    }
    float s1[4] = {0,0,0,0}, s2[4] = {0,0,0,0};
    float s3[4] = {0,0,0,0}, s4[4] = {0,0,0,0};
    #pragma unroll
    for (int k = 0; k < 11; k++) {
        float wk = gw.w[k];
        #pragma unroll
        for (int o = 0; o < 4; o++) {
            s1[o] += wk * p[o + k + 1];
            s2[o] += wk * t[o + k + 1];
            s3[o] += wk * sq[o + k];
            s4[o] += wk * pt[o + k];
        }
    }
    #pragma unroll
    for (int o = 0; o < 4; o++)
        out[o] = make_float4(s1[o], s2[o], s3[o], s4[o]);
}

__global__ __launch_bounds__(256) void ssim_tile_kernel(
    const float* __restrict__ pred, const float* __restrict__ targ,
    float* __restrict__ partial, GaussW gw)
{
    __shared__ __align__(16) float4 hp4[INH * HPC];   // 23.5 KB
    __shared__ float wred[4];

    const int tid = threadIdx.x;
    const int bx = blockIdx.x, by = blockIdx.y, bz = blockIdx.z;
    const int gx0 = bx * TW;
    const int gy0 = by * TH - 5;
    const size_t plane = (size_t)bz * (size_t)(HH * WW);

    const bool interior = (bx >= 1) && (bx <= 14) && (by >= 1) && (by <= 14);

    if (interior) {
        // ---- Phase B fast path: 336 tasks = batch1(256) + batch2(80) ----
        // Issue ALL loads first (2x memory-level parallelism), then compute.
        const int t1 = tid;
        const int r1 = t1 >> 3, c01 = (t1 & 7) << 2;
        const float* prow1 = pred + plane + (size_t)(gy0 + r1) * WW + (gx0 + c01 - 6);
        const float* trow1 = targ + plane + (size_t)(gy0 + r1) * WW + (gx0 + c01 - 6);

        float p1[16], t1v[16];
        *(float2*)&p1[0]   = *(const float2*)(prow1);
        *(float4*)&p1[2]   = *(const float4*)(prow1 + 2);
        *(float4*)&p1[6]   = *(const float4*)(prow1 + 6);
        *(float4*)&p1[10]  = *(const float4*)(prow1 + 10);
        *(float2*)&p1[14]  = *(const float2*)(prow1 + 14);
        *(float2*)&t1v[0]  = *(const float2*)(trow1);
        *(float4*)&t1v[2]  = *(const float4*)(trow1 + 2);
        *(float4*)&t1v[6]  = *(const float4*)(trow1 + 6);
        *(float4*)&t1v[10] = *(const float4*)(trow1 + 10);
        *(float2*)&t1v[14] = *(const float2*)(trow1 + 14);

        float p2[16], t2v[16];
        const bool b2 = (tid < 80);
        if (b2) {
            const int t2 = 256 + tid;
            const int r2 = t2 >> 3, c02 = (t2 & 7) << 2;
            const float* prow2 = pred + plane + (size_t)(gy0 + r2) * WW + (gx0 + c02 - 6);
            const float* trow2 = targ + plane + (size_t)(gy0 + r2) * WW + (gx0 + c02 - 6);
            *(float2*)&p2[0]   = *(const float2*)(prow2);
            *(float4*)&p2[2]   = *(const float4*)(prow2 + 2);
            *(float4*)&p2[6]   = *(const float4*)(prow2 + 6);
            *(float4*)&p2[10]  = *(const float4*)(prow2 + 10);
            *(float2*)&p2[14]  = *(const float2*)(prow2 + 14);
            *(float2*)&t2v[0]  = *(const float2*)(trow2);
            *(float4*)&t2v[2]  = *(const float4*)(trow2 + 2);
            *(float4*)&t2v[6]  = *(const float4*)(trow2 + 6);
            *(float4*)&t2v[10] = *(const float4*)(trow2 + 10);
            *(float2*)&t2v[14] = *(const float2*)(trow2 + 14);
        }

        {
            float4 o[4];
            hconv4(p1, t1v, o, gw);
            float4* dst = &hp4[r1 * HPC + c01];
            dst[0] = o[0]; dst[1] = o[1]; dst[2] = o[2]; dst[3] = o[3];
        }
        if (b2) {
            const int t2 = 256 + tid;
            const int r2 = t2 >> 3, c02 = (t2 & 7) << 2;
            float4 o[4];
            hconv4(p2, t2v, o, gw);
            float4* dst = &hp4[r2 * HPC + c02];
            dst[0] = o[0]; dst[1] = o[1]; dst[2] = o[2]; dst[3] = o[3];
        }
    } else {
        // ---- Phase B generic path: per-element clamp/zero (border blocks) ----
        for (int i = tid; i < INH * 8; i += 256) {
            int r = i >> 3;
            int c0 = (i & 7) << 2;
            int gr = gy0 + r;
            float p[14], t[14];
            if ((unsigned)gr < (unsigned)HH) {
                const size_t rb = plane + (size_t)gr * WW;
                int cbase = gx0 + c0 - 5;
                #pragma unroll
                for (int m = 0; m < 14; m++) {
                    int gc = cbase + m;
                    int cc = min(max(gc, 0), WW - 1);
                    bool in = (unsigned)gc < (unsigned)WW;
                    float pv = pred[rb + cc];
                    float tv = targ[rb + cc];
                    p[m] = in ? pv : 0.f;
                    t[m] = in ? tv : 0.f;
                }
            } else {
                #pragma unroll
                for (int m = 0; m < 14; m++) { p[m] = 0.f; t[m] = 0.f; }
            }

            float s1[4] = {0,0,0,0}, s2[4] = {0,0,0,0};
            float s3[4] = {0,0,0,0}, s4[4] = {0,0,0,0};
            #pragma unroll
            for (int k = 0; k < 11; k++) {
                float wk = gw.w[k];
                #pragma unroll
                for (int o = 0; o < 4; o++) {
                    float pv = p[o + k], tv = t[o + k];
                    float wp = wk * pv, wt = wk * tv;
                    s1[o] += wp;
                    s2[o] += wt;
                    s3[o] += wp * pv + wt * tv;
                    s4[o] += wp * tv;
                }
            }
            float4* dst = &hp4[r * HPC + c0];
            #pragma unroll
            for (int o = 0; o < 4; o++)
                dst[o] = make_float4(s1[o], s2[o], s3[o], s4[o]);
        }
    }
    __syncthreads();

    // ---- Phase C: vertical Gaussian, 4 rows x 1 col per lane, b128 reads ----
    float local = 0.f;
    {
        int c  = tid & 31;          // 0..31
        int r0 = (tid >> 5) << 2;   // 0..28

        float acc[4][4];            // [field][row]
        #pragma unroll
        for (int f = 0; f < 4; f++)
            #pragma unroll
            for (int rr = 0; rr < 4; rr++)
                acc[f][rr] = 0.f;

        const float4* base = &hp4[r0 * HPC + c];
        #pragma unroll
        for (int jj = 0; jj < 14; jj++) {
            float4 v = base[jj * HPC];   // one ds_read_b128: all 4 fields
            #pragma unroll
            for (int rr = 0; rr < 4; rr++) {
                int k = jj - rr;
                if (k >= 0 && k < 11) {
                    float wk = gw.w[k];
                    acc[0][rr] += wk * v.x;
                    acc[1][rr] += wk * v.y;
                    acc[2][rr] += wk * v.z;
                    acc[3][rr] += wk * v.w;
                }
            }
        }

        #pragma unroll
        for (int rr = 0; rr < 4; rr++) {
            float m1 = acc[0][rr], m2 = acc[1][rr];
            float e3 = acc[2][rr], e12 = acc[3][rr];
            float m1s = m1 * m1, m2s = m2 * m2, m12 = m1 * m2;
            float num = (2.f * m12 + C1F) * (2.f * (e12 - m12) + C2F);
            float den = (m1s + m2s + C1F) * (e3 - m1s - m2s + C2F);
            local += num * __builtin_amdgcn_rcpf(den);
        }
    }

    // ---- block reduction ----
    #pragma unroll
    for (int off = 32; off > 0; off >>= 1)
        local += __shfl_down(local, off, 64);
    int lane = tid & 63, wid = tid >> 6;
    if (lane == 0) wred[wid] = local;
    __syncthreads();
    if (tid == 0) {
        int bid = (bz * gridDim.y + by) * gridDim.x + bx;
        partial[bid] = wred[0] + wred[1] + wred[2] + wred[3];
    }
}

__global__ __launch_bounds__(1024) void ssim_finalize_kernel(
    const float* __restrict__ partial, int n, float inv_count,
    float* __restrict__ out)
{
    __shared__ float sm[16];
    float s = 0.f;
    for (int i = threadIdx.x; i < n; i += 1024)
        s += partial[i];
    #pragma unroll
    for (int off = 32; off > 0; off >>= 1)
        s += __shfl_down(s, off, 64);
    int lane = threadIdx.x & 63, wid = threadIdx.x >> 6;
    if (lane == 0) sm[wid] = s;
    __syncthreads();
    if (threadIdx.x == 0) {
        float tot = 0.f;
        #pragma unroll
        for (int k = 0; k < 16; k++) tot += sm[k];
        out[0] = 1.0f - tot * inv_count;
    }
}

extern "C" void kernel_launch(void* const* d_in, const int* in_sizes, int n_in,
                              void* d_out, int out_size, void* d_ws, size_t ws_size,
                              hipStream_t stream)
{
    const float* pred = (const float*)d_in[0];
    const float* targ = (const float*)d_in[1];
    float* out = (float*)d_out;
    float* partial = (float*)d_ws;

    const int total = in_sizes[0];                 // 16*3*512*512 = 12582912
    const int nplanes = total / (HH * WW);         // 48

    GaussW gw;
    double g[11], s = 0.0;
    for (int i = 0; i < 11; i++) {
        double d = (double)(i - 5);
        g[i] = exp(-d * d / 4.5);
        s += g[i];
    }
    for (int i = 0; i < 11; i++) gw.w[i] = (float)(g[i] / s);

    dim3 grid(WW / TW, HH / TH, nplanes);          // 16 x 16 x 48 = 12288 blocks
    ssim_tile_kernel<<<grid, 256, 0, stream>>>(pred, targ, partial, gw);

    const int nblocks = (WW / TW) * (HH / TH) * nplanes;
    const float inv_count = 1.0f / (float)total;
    ssim_finalize_kernel<<<1, 1024, 0, stream>>>(partial, nblocks, inv_count, out);
}

// Round 9
// 193.788 us; speedup vs baseline: 1.1555x; 1.0499x over previous
//
#include <hip/hip_runtime.h>
#include <cmath>

#define HH 512
#define WW 512
#define TW 32
#define TH 54          /* output rows per tile */
#define INH 64         /* TH + 10 halo rows (written) */
#define INHP 66        /* padded rows (safe reads for masked lanes) */
#define HPS 36         /* hp row stride in dwords */
#define GRID_Y 10      /* ceil(512/54) */
#define C1F 0.0001f
#define C2F 0.0009f

struct GaussW { float w[11]; };

__global__ __launch_bounds__(256) void ssim_tile_kernel(
    const float* __restrict__ pred, const float* __restrict__ targ,
    float* __restrict__ partial, GaussW gw)
{
    // planar: hp[field][row][col], 4 x 66 x 36 dwords = 38016 B
    __shared__ __align__(16) float hp[4][INHP][HPS];
    __shared__ float wred[4];

    const int tid = threadIdx.x;
    const int bx = blockIdx.x, by = blockIdx.y, bz = blockIdx.z;
    const int gx0 = bx * TW;
    const int gy0 = by * TH - 5;
    const size_t plane = (size_t)bz * (size_t)(HH * WW);

    const bool xinterior = (bx > 0) && (bx < (WW / TW) - 1);

    if (xinterior) {
        // ---- Phase B fast path: exactly 2 full rounds of 256 tasks ----
        // Task (r, c0): horizontal conv for row r, output cols c0..c0+3.
        // Branch-free y: clamped-address loads, mask conv outputs by row validity.
        const int r1 = tid >> 3;             // 0..31
        const int c0 = (tid & 7) << 2;       // 0..28
        const int gr1 = gy0 + r1;
        const int gr2 = gr1 + 32;
        const int gc1 = min(max(gr1, 0), HH - 1);
        const int gc2 = min(max(gr2, 0), HH - 1);
        const float rm1 = ((unsigned)gr1 < (unsigned)HH) ? 1.f : 0.f;
        const float rm2 = ((unsigned)gr2 < (unsigned)HH) ? 1.f : 0.f;

        const float* prow1 = pred + plane + (size_t)gc1 * WW + (gx0 + c0 - 6);
        const float* trow1 = targ + plane + (size_t)gc1 * WW + (gx0 + c0 - 6);
        const float* prow2 = pred + plane + (size_t)gc2 * WW + (gx0 + c0 - 6);
        const float* trow2 = targ + plane + (size_t)gc2 * WW + (gx0 + c0 - 6);

        float p1[16], t1[16], p2[16], t2[16];
        *(float2*)&p1[0]  = *(const float2*)(prow1);
        *(float4*)&p1[2]  = *(const float4*)(prow1 + 2);
        *(float4*)&p1[6]  = *(const float4*)(prow1 + 6);
        *(float4*)&p1[10] = *(const float4*)(prow1 + 10);
        *(float2*)&p1[14] = *(const float2*)(prow1 + 14);
        *(float2*)&t1[0]  = *(const float2*)(trow1);
        *(float4*)&t1[2]  = *(const float4*)(trow1 + 2);
        *(float4*)&t1[6]  = *(const float4*)(trow1 + 6);
        *(float4*)&t1[10] = *(const float4*)(trow1 + 10);
        *(float2*)&t1[14] = *(const float2*)(trow1 + 14);
        *(float2*)&p2[0]  = *(const float2*)(prow2);
        *(float4*)&p2[2]  = *(const float4*)(prow2 + 2);
        *(float4*)&p2[6]  = *(const float4*)(prow2 + 6);
        *(float4*)&p2[10] = *(const float4*)(prow2 + 10);
        *(float2*)&p2[14] = *(const float2*)(prow2 + 14);
        *(float2*)&t2[0]  = *(const float2*)(trow2);
        *(float4*)&t2[2]  = *(const float4*)(trow2 + 2);
        *(float4*)&t2[6]  = *(const float4*)(trow2 + 6);
        *(float4*)&t2[10] = *(const float4*)(trow2 + 10);
        *(float2*)&t2[14] = *(const float2*)(trow2 + 14);

        #pragma unroll
        for (int rd = 0; rd < 2; rd++) {
            const float* p = rd ? p2 : p1;
            const float* t = rd ? t2 : t1;
            const float rm = rd ? rm2 : rm1;
            const int r = rd ? (r1 + 32) : r1;

            float sq[14], pt[14];
            #pragma unroll
            for (int m = 0; m < 14; m++) {
                float pv = p[m + 1], tv = t[m + 1];
                sq[m] = pv * pv + tv * tv;
                pt[m] = pv * tv;
            }
            float s1[4] = {0,0,0,0}, s2[4] = {0,0,0,0};
            float s3[4] = {0,0,0,0}, s4[4] = {0,0,0,0};
            #pragma unroll
            for (int k = 0; k < 11; k++) {
                float wk = gw.w[k];
                #pragma unroll
                for (int o = 0; o < 4; o++) {
                    s1[o] += wk * p[o + k + 1];
                    s2[o] += wk * t[o + k + 1];
                    s3[o] += wk * sq[o + k];
                    s4[o] += wk * pt[o + k];
                }
            }
            *(float4*)&hp[0][r][c0] = make_float4(rm*s1[0], rm*s1[1], rm*s1[2], rm*s1[3]);
            *(float4*)&hp[1][r][c0] = make_float4(rm*s2[0], rm*s2[1], rm*s2[2], rm*s2[3]);
            *(float4*)&hp[2][r][c0] = make_float4(rm*s3[0], rm*s3[1], rm*s3[2], rm*s3[3]);
            *(float4*)&hp[3][r][c0] = make_float4(rm*s4[0], rm*s4[1], rm*s4[2], rm*s4[3]);
        }
    } else {
        // ---- Phase B generic path (bx = 0 or 15): per-element clamp/zero ----
        #pragma unroll
        for (int it = 0; it < 2; it++) {
            int i = tid + it * 256;
            int r = i >> 3;
            int c0 = (i & 7) << 2;
            int gr = gy0 + r;
            float p[14], t[14];
            if ((unsigned)gr < (unsigned)HH) {
                const size_t rb = plane + (size_t)gr * WW;
                int cbase = gx0 + c0 - 5;
                #pragma unroll
                for (int m = 0; m < 14; m++) {
                    int gc = cbase + m;
                    int cc = min(max(gc, 0), WW - 1);
                    bool in = (unsigned)gc < (unsigned)WW;
                    float pv = pred[rb + cc];
                    float tv = targ[rb + cc];
                    p[m] = in ? pv : 0.f;
                    t[m] = in ? tv : 0.f;
                }
            } else {
                #pragma unroll
                for (int m = 0; m < 14; m++) { p[m] = 0.f; t[m] = 0.f; }
            }
            float s1[4] = {0,0,0,0}, s2[4] = {0,0,0,0};
            float s3[4] = {0,0,0,0}, s4[4] = {0,0,0,0};
            #pragma unroll
            for (int k = 0; k < 11; k++) {
                float wk = gw.w[k];
                #pragma unroll
                for (int o = 0; o < 4; o++) {
                    float pv = p[o + k], tv = t[o + k];
                    float wp = wk * pv, wt = wk * tv;
                    s1[o] += wp;
                    s2[o] += wt;
                    s3[o] += wp * pv + wt * tv;
                    s4[o] += wp * tv;
                }
            }
            *(float4*)&hp[0][r][c0] = make_float4(s1[0], s1[1], s1[2], s1[3]);
            *(float4*)&hp[1][r][c0] = make_float4(s2[0], s2[1], s2[2], s2[3]);
            *(float4*)&hp[2][r][c0] = make_float4(s3[0], s3[1], s3[2], s3[3]);
            *(float4*)&hp[3][r][c0] = make_float4(s4[0], s4[1], s4[2], s4[3]);
        }
    }
    __syncthreads();

    // ---- Phase C: vertical conv, 7-row x 1-col strip per lane + SSIM ----
    float local = 0.f;
    {
        const int c  = tid & 31;          // 0..31
        const int r0 = (tid >> 5) * 7;    // 0,7,...,49

        float acc[4][7];
        #pragma unroll
        for (int f = 0; f < 4; f++)
            #pragma unroll
            for (int rr = 0; rr < 7; rr++)
                acc[f][rr] = 0.f;

        #pragma unroll
        for (int j = 0; j < 17; j++) {
            float v0 = hp[0][r0 + j][c];
            float v1 = hp[1][r0 + j][c];
            float v2 = hp[2][r0 + j][c];
            float v3 = hp[3][r0 + j][c];
            #pragma unroll
            for (int rr = 0; rr < 7; rr++) {
                int k = j - rr;
                if (k >= 0 && k < 11) {
                    float wk = gw.w[k];
                    acc[0][rr] += wk * v0;
                    acc[1][rr] += wk * v1;
                    acc[2][rr] += wk * v2;
                    acc[3][rr] += wk * v3;
                }
            }
        }

        const int gybase = by * TH;
        #pragma unroll
        for (int rr = 0; rr < 7; rr++) {
            int r = r0 + rr;
            bool valid = (r < TH) && (gybase + r < HH);
            float m1 = acc[0][rr], m2 = acc[1][rr];
            float e3 = acc[2][rr], e12 = acc[3][rr];
            float m1s = m1 * m1, m2s = m2 * m2, m12 = m1 * m2;
            float num = (2.f * m12 + C1F) * (2.f * (e12 - m12) + C2F);
            float den = (m1s + m2s + C1F) * (e3 - m1s - m2s + C2F);
            float v = num * __builtin_amdgcn_rcpf(den);
            local += valid ? v : 0.f;
        }
    }

    // ---- block reduction ----
    #pragma unroll
    for (int off = 32; off > 0; off >>= 1)
        local += __shfl_down(local, off, 64);
    int lane = tid & 63, wid = tid >> 6;
    if (lane == 0) wred[wid] = local;
    __syncthreads();
    if (tid == 0) {
        int bid = (bz * gridDim.y + by) * gridDim.x + bx;
        partial[bid] = wred[0] + wred[1] + wred[2] + wred[3];
    }
}

__global__ __launch_bounds__(1024) void ssim_finalize_kernel(
    const float* __restrict__ partial, int n, float inv_count,
    float* __restrict__ out)
{
    __shared__ float sm[16];
    float s = 0.f;
    for (int i = threadIdx.x; i < n; i += 1024)
        s += partial[i];
    #pragma unroll
    for (int off = 32; off > 0; off >>= 1)
        s += __shfl_down(s, off, 64);
    int lane = threadIdx.x & 63, wid = threadIdx.x >> 6;
    if (lane == 0) sm[wid] = s;
    __syncthreads();
    if (threadIdx.x == 0) {
        float tot = 0.f;
        #pragma unroll
        for (int k = 0; k < 16; k++) tot += sm[k];
        out[0] = 1.0f - tot * inv_count;
    }
}

extern "C" void kernel_launch(void* const* d_in, const int* in_sizes, int n_in,
                              void* d_out, int out_size, void* d_ws, size_t ws_size,
                              hipStream_t stream)
{
    const float* pred = (const float*)d_in[0];
    const float* targ = (const float*)d_in[1];
    float* out = (float*)d_out;
    float* partial = (float*)d_ws;

    const int total = in_sizes[0];                 // 16*3*512*512 = 12582912
    const int nplanes = total / (HH * WW);         // 48

    GaussW gw;
    double g[11], s = 0.0;
    for (int i = 0; i < 11; i++) {
        double d = (double)(i - 5);
        g[i] = exp(-d * d / 4.5);
        s += g[i];
    }
    for (int i = 0; i < 11; i++) gw.w[i] = (float)(g[i] / s);

    dim3 grid(WW / TW, GRID_Y, nplanes);           // 16 x 10 x 48 = 7680 blocks
    ssim_tile_kernel<<<grid, 256, 0, stream>>>(pred, targ, partial, gw);

    const int nblocks = (WW / TW) * GRID_Y * nplanes;
    const float inv_count = 1.0f / (float)total;
    ssim_finalize_kernel<<<1, 1024, 0, stream>>>(partial, nblocks, inv_count, out);
}